// Round 1
// baseline (1263.049 us; speedup 1.0000x reference)
//
#include <hip/hip_runtime.h>
#include <math.h>

#define NN 32000
#define NE 320000
#define NG 1600

// h[n,c] = emb[x[n],c]; accum = 0
__global__ __launch_bounds__(256) void k_embed(const int* __restrict__ x,
                                               const float* __restrict__ emb,
                                               float* __restrict__ h,
                                               float* __restrict__ accum) {
  int idx = blockIdx.x * 256 + threadIdx.x;   // float4 index, total 1,024,000
  int n = idx >> 5;
  int c4 = (idx & 31) << 2;
  float4 v = *(const float4*)(emb + (size_t)x[n] * 128 + c4);
  *(float4*)(h + (size_t)n * 128 + c4) = v;
  *(float4*)(accum + (size_t)n * 128 + c4) = make_float4(0.f, 0.f, 0.f, 0.f);
}

// T[32000,512] = H[32000,128] @ [Wf[0:128] | Wf[128:256] | Ws[0:128] | Ws[128:256]]
__global__ __launch_bounds__(256) void k_gemm(const float* __restrict__ H,
                                              const float* __restrict__ Wf,
                                              const float* __restrict__ Ws,
                                              float* __restrict__ T) {
  __shared__ float As[64][36];
  __shared__ float Bs[32][68];
  int bm = blockIdx.x;
  int n0 = blockIdx.y * 64;
  const float* Wbase;
  {
    int seg = n0 >> 7;  // 0..3
    Wbase = (seg == 0) ? Wf : (seg == 1) ? (Wf + 128 * 128)
            : (seg == 2) ? Ws : (Ws + 128 * 128);
  }
  int ncol = n0 & 127;
  int tid = threadIdx.x;
  int tx = tid & 15, ty = tid >> 4;
  float acc[4][4] = {};
  const float* Hbase = H + (size_t)bm * 64 * 128;
  for (int kk = 0; kk < 128; kk += 32) {
#pragma unroll
    for (int i = 0; i < 2; ++i) {
      int idx = tid + i * 256;
      int r = idx >> 3, c4 = (idx & 7) << 2;
      float4 v = *(const float4*)(Hbase + r * 128 + kk + c4);
      *(float4*)&As[r][c4] = v;
    }
#pragma unroll
    for (int i = 0; i < 2; ++i) {
      int idx = tid + i * 256;
      int kr = idx >> 4, c4 = (idx & 15) << 2;
      float4 v = *(const float4*)(Wbase + (size_t)(kk + kr) * 128 + ncol + c4);
      *(float4*)&Bs[kr][c4] = v;
    }
    __syncthreads();
#pragma unroll
    for (int k = 0; k < 32; ++k) {
      float4 b = *(float4*)&Bs[k][tx << 2];
      float a0 = As[(ty << 2) + 0][k];
      float a1 = As[(ty << 2) + 1][k];
      float a2 = As[(ty << 2) + 2][k];
      float a3 = As[(ty << 2) + 3][k];
      acc[0][0] += a0 * b.x; acc[0][1] += a0 * b.y; acc[0][2] += a0 * b.z; acc[0][3] += a0 * b.w;
      acc[1][0] += a1 * b.x; acc[1][1] += a1 * b.y; acc[1][2] += a1 * b.z; acc[1][3] += a1 * b.w;
      acc[2][0] += a2 * b.x; acc[2][1] += a2 * b.y; acc[2][2] += a2 * b.z; acc[2][3] += a2 * b.w;
      acc[3][0] += a3 * b.x; acc[3][1] += a3 * b.y; acc[3][2] += a3 * b.z; acc[3][3] += a3 * b.w;
    }
    __syncthreads();
  }
#pragma unroll
  for (int i = 0; i < 4; ++i) {
    float4 v = make_float4(acc[i][0], acc[i][1], acc[i][2], acc[i][3]);
    *(float4*)(T + (size_t)(bm * 64 + (ty << 2) + i) * 512 + n0 + (tx << 2)) = v;
  }
}

// Per-edge: pre_f = T[d,c] + T[s,128+c] + ea@Wfe + bf ; pre_s = T[d,256+c] + T[s,384+c] + ea@Wse + bs
// msg = sigmoid(pre_f) * softplus(pre_s); atomicAdd accum[d]
__global__ __launch_bounds__(256) void k_edge(const int* __restrict__ ei,
                                              const float* __restrict__ ea,
                                              const float* __restrict__ T,
                                              const float* __restrict__ Wfe,
                                              const float* __restrict__ Wse,
                                              const float* __restrict__ bf,
                                              const float* __restrict__ bs,
                                              float* __restrict__ accum) {
  __shared__ float sWf[32 * 128];
  __shared__ float sWs[32 * 128];
  __shared__ float sEa[64 * 32];
  __shared__ float sbf[128], sbs[128];
  __shared__ int sSrc[64], sDst[64];
  int tid = threadIdx.x;
  int e0 = blockIdx.x * 64;
#pragma unroll
  for (int i = 0; i < 4; ++i) {
    int o = (tid + i * 256) << 2;
    *(float4*)&sWf[o] = *(const float4*)(Wfe + o);
    *(float4*)&sWs[o] = *(const float4*)(Wse + o);
  }
#pragma unroll
  for (int i = 0; i < 2; ++i) {
    int o = (tid + i * 256) << 2;
    *(float4*)&sEa[o] = *(const float4*)(ea + (size_t)e0 * 32 + o);
  }
  if (tid < 128) {
    sbf[tid] = bf[tid];
    sbs[tid] = bs[tid];
  } else if (tid < 192) {
    sSrc[tid - 128] = ei[e0 + tid - 128];
  } else if (tid < 256) {
    sDst[tid - 192] = ei[NE + e0 + tid - 192];
  }
  __syncthreads();
  int w = tid >> 6, lane = tid & 63;
  int c = lane << 1;
  float bf0 = sbf[c], bf1 = sbf[c + 1], bs0 = sbs[c], bs1 = sbs[c + 1];
#pragma unroll 1
  for (int g = 0; g < 4; ++g) {
    int elb = w * 16 + g * 4;
    float2 cf[4], cs[4];
#pragma unroll
    for (int j = 0; j < 4; ++j) {
      cf[j] = make_float2(0.f, 0.f);
      cs[j] = make_float2(0.f, 0.f);
    }
#pragma unroll
    for (int k = 0; k < 32; ++k) {
      float2 wf = *(const float2*)&sWf[k * 128 + c];
      float2 ws = *(const float2*)&sWs[k * 128 + c];
#pragma unroll
      for (int j = 0; j < 4; ++j) {
        float a = sEa[(elb + j) * 32 + k];
        cf[j].x += a * wf.x; cf[j].y += a * wf.y;
        cs[j].x += a * ws.x; cs[j].y += a * ws.y;
      }
    }
#pragma unroll
    for (int j = 0; j < 4; ++j) {
      int s = sSrc[elb + j], d = sDst[elb + j];
      const float* Td = T + (size_t)d * 512;
      const float* Tsrc = T + (size_t)s * 512;
      float2 fd = *(const float2*)(Td + c);
      float2 fs = *(const float2*)(Tsrc + 128 + c);
      float2 sd = *(const float2*)(Td + 256 + c);
      float2 ss = *(const float2*)(Tsrc + 384 + c);
      float xf0 = fd.x + fs.x + cf[j].x + bf0;
      float xf1 = fd.y + fs.y + cf[j].y + bf1;
      float xs0 = sd.x + ss.x + cs[j].x + bs0;
      float xs1 = sd.y + ss.y + cs[j].y + bs1;
      float g0 = 1.f / (1.f + expf(-xf0));
      float g1 = 1.f / (1.f + expf(-xf1));
      float sp0 = fmaxf(xs0, 0.f) + log1pf(expf(-fabsf(xs0)));
      float sp1 = fmaxf(xs1, 0.f) + log1pf(expf(-fabsf(xs1)));
      float m0 = g0 * sp0, m1 = g1 * sp1;
      atomicAdd(accum + (size_t)d * 128 + c, m0);
      atomicAdd(accum + (size_t)d * 128 + c + 1, m1);
    }
  }
}

// h = relu(h + accum); accum = 0
__global__ __launch_bounds__(256) void k_update(float* __restrict__ h,
                                                float* __restrict__ accum) {
  size_t idx = ((size_t)blockIdx.x * 256 + threadIdx.x) << 2;
  float4 a = *(float4*)(accum + idx);
  float4 v = *(float4*)(h + idx);
  v.x = fmaxf(v.x + a.x, 0.f);
  v.y = fmaxf(v.y + a.y, 0.f);
  v.z = fmaxf(v.z + a.z, 0.f);
  v.w = fmaxf(v.w + a.w, 0.f);
  *(float4*)(h + idx) = v;
  *(float4*)(accum + idx) = make_float4(0.f, 0.f, 0.f, 0.f);
}

__global__ __launch_bounds__(256) void k_pool(const float* __restrict__ h,
                                              const int* __restrict__ batch,
                                              float* __restrict__ sums,
                                              float* __restrict__ cnt) {
  int n = blockIdx.x * 2 + (threadIdx.x >> 7);
  int c = threadIdx.x & 127;
  int g = batch[n];
  atomicAdd(sums + (size_t)g * 128 + c, h[(size_t)n * 128 + c]);
  if (c == 0) atomicAdd(cnt + g, 1.f);
}

__global__ __launch_bounds__(128) void k_final(const float* __restrict__ sums,
                                               const float* __restrict__ cnt,
                                               const float* __restrict__ Wlin,
                                               const float* __restrict__ blin,
                                               float* __restrict__ out) {
  __shared__ float p[128];
  int g = blockIdx.x, c = threadIdx.x;
  float inv = 1.f / fmaxf(cnt[g], 1.f);
  p[c] = sums[(size_t)g * 128 + c] * inv;
  __syncthreads();
  float acc = blin[c];
#pragma unroll 8
  for (int k = 0; k < 128; ++k) acc += p[k] * Wlin[k * 128 + c];
  out[(size_t)g * 128 + c] = acc;
}

extern "C" void kernel_launch(void* const* d_in, const int* in_sizes, int n_in,
                              void* d_out, int out_size, void* d_ws, size_t ws_size,
                              hipStream_t stream) {
  const int* x = (const int*)d_in[0];
  const int* ei = (const int*)d_in[1];
  const float* ea = (const float*)d_in[2];
  const int* batch = (const int*)d_in[3];
  const float* emb = (const float*)d_in[4];
  const float* Wf[3] = {(const float*)d_in[5], (const float*)d_in[9], (const float*)d_in[13]};
  const float* bf[3] = {(const float*)d_in[6], (const float*)d_in[10], (const float*)d_in[14]};
  const float* Wsm[3] = {(const float*)d_in[7], (const float*)d_in[11], (const float*)d_in[15]};
  const float* bs[3] = {(const float*)d_in[8], (const float*)d_in[12], (const float*)d_in[16]};
  const float* Wlin = (const float*)d_in[17];
  const float* blin = (const float*)d_in[18];
  float* out = (float*)d_out;

  char* ws = (char*)d_ws;
  const size_t HBYTES = (size_t)NN * 128 * sizeof(float);        // 16,384,000
  const size_t TBYTES = (size_t)NN * 512 * sizeof(float);        // 65,536,000
  float* h = (float*)ws;
  float* accum = (float*)(ws + HBYTES);
  float* T = (float*)(ws + 2 * HBYTES);
  float* sums = (float*)(ws + 2 * HBYTES + TBYTES);
  float* cnt = sums + (size_t)NG * 128;

  hipMemsetAsync(sums, 0, ((size_t)NG * 128 + NG) * sizeof(float), stream);
  k_embed<<<4000, 256, 0, stream>>>(x, emb, h, accum);
  for (int l = 0; l < 3; ++l) {
    k_gemm<<<dim3(500, 8), 256, 0, stream>>>(h, Wf[l], Wsm[l], T);
    k_edge<<<5000, 256, 0, stream>>>(ei, ea, T, Wf[l] + 256 * 128, Wsm[l] + 256 * 128,
                                     bf[l], bs[l], accum);
    k_update<<<4000, 256, 0, stream>>>(h, accum);
  }
  k_pool<<<16000, 256, 0, stream>>>(h, batch, sums, cnt);
  k_final<<<1600, 128, 0, stream>>>(sums, cnt, Wlin, blin, out);
}

// Round 2
// 786.433 us; speedup vs baseline: 1.6060x; 1.6060x over previous
//
#include <hip/hip_runtime.h>
#include <math.h>

#define NN 32000
#define NE 320000
#define NG 1600

using frag_ab = __attribute__((ext_vector_type(8))) short;   // 8 bf16 (4 VGPRs)
using frag_cd = __attribute__((ext_vector_type(4))) float;   // 4 fp32

static __device__ __forceinline__ unsigned short f2bf(float f) {
  unsigned u = __builtin_bit_cast(unsigned, f);
  unsigned r = u + 0x7fff + ((u >> 16) & 1);   // RNE
  return (unsigned short)(r >> 16);
}

// h[n,c] = emb[x[n],c]; accum = 0
__global__ __launch_bounds__(256) void k_embed(const int* __restrict__ x,
                                               const float* __restrict__ emb,
                                               float* __restrict__ h,
                                               float* __restrict__ accum) {
  int idx = blockIdx.x * 256 + threadIdx.x;   // float4 index, total 1,024,000
  int n = idx >> 5;
  int c4 = (idx & 31) << 2;
  float4 v = *(const float4*)(emb + (size_t)x[n] * 128 + c4);
  *(float4*)(h + (size_t)n * 128 + c4) = v;
  *(float4*)(accum + (size_t)n * 128 + c4) = make_float4(0.f, 0.f, 0.f, 0.f);
}

// Pack ea-rows (256..287) of Wf/Ws into bf16, col-major [cc][k], tile-interleaved:
// cc = w*64 + t*16 + c ; t in {0,1} -> Wf col (w*32 + t*16 + c); t in {2,3} -> Ws col (w*32+(t-2)*16+c)
__global__ __launch_bounds__(256) void k_prep_w(const float* __restrict__ Wf1, const float* __restrict__ Ws1,
                                                const float* __restrict__ Wf2, const float* __restrict__ Ws2,
                                                const float* __restrict__ Wf3, const float* __restrict__ Ws3,
                                                unsigned short* __restrict__ wpack) {
  int idx = blockIdx.x * 256 + threadIdx.x;    // 3*8192 = 24576
  int l = idx >> 13;
  int r = idx & 8191;
  int cc = r >> 5;
  int k = r & 31;
  int w = cc >> 6, t = (cc >> 4) & 3, c = cc & 15;
  const float* Wf = (l == 0) ? Wf1 : (l == 1) ? Wf2 : Wf3;
  const float* Ws = (l == 0) ? Ws1 : (l == 1) ? Ws2 : Ws3;
  const float* W = (t < 2) ? Wf : Ws;
  int ch = w * 32 + (t & 1) * 16 + c;
  wpack[(size_t)l * 8192 + cc * 32 + k] = f2bf(W[(size_t)(256 + k) * 128 + ch]);
}

// T[32000,512] = H[32000,128] @ [Wf[0:128] | Wf[128:256] | Ws[0:128] | Ws[128:256]]
__global__ __launch_bounds__(256) void k_gemm(const float* __restrict__ H,
                                              const float* __restrict__ Wf,
                                              const float* __restrict__ Ws,
                                              float* __restrict__ T) {
  __shared__ float As[64][36];
  __shared__ float Bs[32][68];
  int bm = blockIdx.x;
  int n0 = blockIdx.y * 64;
  const float* Wbase;
  {
    int seg = n0 >> 7;  // 0..3
    Wbase = (seg == 0) ? Wf : (seg == 1) ? (Wf + 128 * 128)
            : (seg == 2) ? Ws : (Ws + 128 * 128);
  }
  int ncol = n0 & 127;
  int tid = threadIdx.x;
  int tx = tid & 15, ty = tid >> 4;
  float acc[4][4] = {};
  const float* Hbase = H + (size_t)bm * 64 * 128;
  for (int kk = 0; kk < 128; kk += 32) {
#pragma unroll
    for (int i = 0; i < 2; ++i) {
      int idx = tid + i * 256;
      int r = idx >> 3, c4 = (idx & 7) << 2;
      float4 v = *(const float4*)(Hbase + r * 128 + kk + c4);
      *(float4*)&As[r][c4] = v;
    }
#pragma unroll
    for (int i = 0; i < 2; ++i) {
      int idx = tid + i * 256;
      int kr = idx >> 4, c4 = (idx & 15) << 2;
      float4 v = *(const float4*)(Wbase + (size_t)(kk + kr) * 128 + ncol + c4);
      *(float4*)&Bs[kr][c4] = v;
    }
    __syncthreads();
#pragma unroll
    for (int k = 0; k < 32; ++k) {
      float4 b = *(float4*)&Bs[k][tx << 2];
      float a0 = As[(ty << 2) + 0][k];
      float a1 = As[(ty << 2) + 1][k];
      float a2 = As[(ty << 2) + 2][k];
      float a3 = As[(ty << 2) + 3][k];
      acc[0][0] += a0 * b.x; acc[0][1] += a0 * b.y; acc[0][2] += a0 * b.z; acc[0][3] += a0 * b.w;
      acc[1][0] += a1 * b.x; acc[1][1] += a1 * b.y; acc[1][2] += a1 * b.z; acc[1][3] += a1 * b.w;
      acc[2][0] += a2 * b.x; acc[2][1] += a2 * b.y; acc[2][2] += a2 * b.z; acc[2][3] += a2 * b.w;
      acc[3][0] += a3 * b.x; acc[3][1] += a3 * b.y; acc[3][2] += a3 * b.z; acc[3][3] += a3 * b.w;
    }
    __syncthreads();
  }
#pragma unroll
  for (int i = 0; i < 4; ++i) {
    float4 v = make_float4(acc[i][0], acc[i][1], acc[i][2], acc[i][3]);
    *(float4*)(T + (size_t)(bm * 64 + (ty << 2) + i) * 512 + n0 + (tx << 2)) = v;
  }
}

// Per-edge with MFMA ea@We term.
// Block = 4 waves, 64 edges. Wave w covers output channels [w*32, w*32+32).
__global__ __launch_bounds__(256) void k_edge(const int* __restrict__ ei,
                                              const float* __restrict__ ea,
                                              const float* __restrict__ T,
                                              const unsigned short* __restrict__ wpackL,
                                              const float* __restrict__ bf,
                                              const float* __restrict__ bs,
                                              float* __restrict__ accum) {
  __shared__ short sA[64 * 40];    // ea tile bf16, row stride 40 (pad 8)
  __shared__ short sB[256 * 40];   // packed W bf16, col stride 40
  __shared__ float sbf[128], sbs[128];
  __shared__ int sSrc[64], sDst[64];
  int tid = threadIdx.x;
  int e0 = blockIdx.x * 64;

  // stage ea tile: 64 rows x 32 fp32 -> bf16
#pragma unroll
  for (int i = 0; i < 2; ++i) {
    int idx = tid + i * 256;            // 0..511
    int row = idx >> 3, qq = idx & 7;   // 8 float4 chunks per row
    float4 v = *(const float4*)(ea + (size_t)(e0 + row) * 32 + qq * 4);
    ushort4 o;
    o.x = f2bf(v.x); o.y = f2bf(v.y); o.z = f2bf(v.z); o.w = f2bf(v.w);
    *(ushort4*)&sA[row * 40 + qq * 4] = o;
  }
  // stage packed weights: 256 cols x 32 k bf16 (16 KB)
#pragma unroll
  for (int i = 0; i < 4; ++i) {
    int idx = tid + i * 256;            // 0..1023
    int col = idx >> 2, qq = idx & 3;   // 4 x 8-elem chunks per col
    uint4 v = *(const uint4*)(wpackL + (size_t)col * 32 + qq * 8);
    *(uint4*)&sB[col * 40 + qq * 8] = v;
  }
  if (tid < 128) {
    sbf[tid] = bf[tid];
    sbs[tid] = bs[tid];
  } else if (tid < 192) {
    sSrc[tid - 128] = ei[e0 + tid - 128];
  } else {
    sDst[tid - 192] = ei[NE + e0 + tid - 192];
  }
  __syncthreads();

  int w = tid >> 6;
  int lane = tid & 63;
  int c = lane & 15;      // A-row / B-col / C-col within tile
  int q = lane >> 4;      // quad: k-offset for A/B, row group for C

  // fragments
  frag_ab Af[4], Bf[4];
#pragma unroll
  for (int et = 0; et < 4; ++et)
    Af[et] = *(const frag_ab*)&sA[(et * 16 + c) * 40 + q * 8];
#pragma unroll
  for (int t = 0; t < 4; ++t)
    Bf[t] = *(const frag_ab*)&sB[(w * 64 + t * 16 + c) * 40 + q * 8];

  frag_cd acc[4][4];
#pragma unroll
  for (int et = 0; et < 4; ++et)
#pragma unroll
    for (int t = 0; t < 4; ++t)
      acc[et][t] = (frag_cd){0.f, 0.f, 0.f, 0.f};

#pragma unroll
  for (int et = 0; et < 4; ++et)
#pragma unroll
    for (int t = 0; t < 4; ++t)
      acc[et][t] = __builtin_amdgcn_mfma_f32_16x16x32_bf16(Af[et], Bf[t], acc[et][t], 0, 0, 0);

  // biases for this lane's two channels
  int ch0 = w * 32 + c;
  float bf_0 = sbf[ch0], bf_1 = sbf[ch0 + 16];
  float bs_0 = sbs[ch0], bs_1 = sbs[ch0 + 16];

  // epilogue: e = et*16 + q*4 + r ; t pair (t, t+2) = (f, s) at channel ch0 + t*16
#pragma unroll
  for (int et = 0; et < 4; ++et) {
#pragma unroll
    for (int r = 0; r < 4; ++r) {
      int e = et * 16 + q * 4 + r;
      int s = sSrc[e], d = sDst[e];
      const float* Td = T + (size_t)d * 512;
      const float* Tsrc = T + (size_t)s * 512;
#pragma unroll
      for (int t = 0; t < 2; ++t) {
        int ch = ch0 + t * 16;
        float xf = acc[et][t][r]     + Td[ch]       + Tsrc[128 + ch] + (t ? bf_1 : bf_0);
        float xs = acc[et][t + 2][r] + Td[256 + ch] + Tsrc[384 + ch] + (t ? bs_1 : bs_0);
        float sig = __builtin_amdgcn_rcpf(1.f + __expf(-xf));
        float sp = fmaxf(xs, 0.f) + __logf(1.f + __expf(-fabsf(xs)));
        atomicAdd(accum + (size_t)d * 128 + ch, sig * sp);
      }
    }
  }
}

// h = relu(h + accum); accum = 0
__global__ __launch_bounds__(256) void k_update(float* __restrict__ h,
                                                float* __restrict__ accum) {
  size_t idx = ((size_t)blockIdx.x * 256 + threadIdx.x) << 2;
  float4 a = *(float4*)(accum + idx);
  float4 v = *(float4*)(h + idx);
  v.x = fmaxf(v.x + a.x, 0.f);
  v.y = fmaxf(v.y + a.y, 0.f);
  v.z = fmaxf(v.z + a.z, 0.f);
  v.w = fmaxf(v.w + a.w, 0.f);
  *(float4*)(h + idx) = v;
  *(float4*)(accum + idx) = make_float4(0.f, 0.f, 0.f, 0.f);
}

__global__ __launch_bounds__(256) void k_pool(const float* __restrict__ h,
                                              const int* __restrict__ batch,
                                              float* __restrict__ sums,
                                              float* __restrict__ cnt) {
  int n = blockIdx.x * 2 + (threadIdx.x >> 7);
  int c = threadIdx.x & 127;
  int g = batch[n];
  atomicAdd(sums + (size_t)g * 128 + c, h[(size_t)n * 128 + c]);
  if (c == 0) atomicAdd(cnt + g, 1.f);
}

__global__ __launch_bounds__(128) void k_final(const float* __restrict__ sums,
                                               const float* __restrict__ cnt,
                                               const float* __restrict__ Wlin,
                                               const float* __restrict__ blin,
                                               float* __restrict__ out) {
  __shared__ float p[128];
  int g = blockIdx.x, c = threadIdx.x;
  float inv = 1.f / fmaxf(cnt[g], 1.f);
  p[c] = sums[(size_t)g * 128 + c] * inv;
  __syncthreads();
  float acc = blin[c];
#pragma unroll 8
  for (int k = 0; k < 128; ++k) acc += p[k] * Wlin[k * 128 + c];
  out[(size_t)g * 128 + c] = acc;
}

extern "C" void kernel_launch(void* const* d_in, const int* in_sizes, int n_in,
                              void* d_out, int out_size, void* d_ws, size_t ws_size,
                              hipStream_t stream) {
  const int* x = (const int*)d_in[0];
  const int* ei = (const int*)d_in[1];
  const float* ea = (const float*)d_in[2];
  const int* batch = (const int*)d_in[3];
  const float* emb = (const float*)d_in[4];
  const float* Wf[3] = {(const float*)d_in[5], (const float*)d_in[9], (const float*)d_in[13]};
  const float* bf[3] = {(const float*)d_in[6], (const float*)d_in[10], (const float*)d_in[14]};
  const float* Wsm[3] = {(const float*)d_in[7], (const float*)d_in[11], (const float*)d_in[15]};
  const float* bs[3] = {(const float*)d_in[8], (const float*)d_in[12], (const float*)d_in[16]};
  const float* Wlin = (const float*)d_in[17];
  const float* blin = (const float*)d_in[18];
  float* out = (float*)d_out;

  char* ws = (char*)d_ws;
  const size_t HBYTES = (size_t)NN * 128 * sizeof(float);        // 16,384,000
  const size_t TBYTES = (size_t)NN * 512 * sizeof(float);        // 65,536,000
  float* h = (float*)ws;
  float* accum = (float*)(ws + HBYTES);
  float* T = (float*)(ws + 2 * HBYTES);
  float* sums = (float*)(ws + 2 * HBYTES + TBYTES);
  float* cnt = sums + (size_t)NG * 128;
  unsigned short* wpack = (unsigned short*)(ws + 2 * HBYTES + TBYTES + ((size_t)NG * 128 + NG + 2) * sizeof(float));

  hipMemsetAsync(sums, 0, ((size_t)NG * 128 + NG) * sizeof(float), stream);
  k_prep_w<<<96, 256, 0, stream>>>(Wf[0], Wsm[0], Wf[1], Wsm[1], Wf[2], Wsm[2], wpack);
  k_embed<<<4000, 256, 0, stream>>>(x, emb, h, accum);
  for (int l = 0; l < 3; ++l) {
    k_gemm<<<dim3(500, 8), 256, 0, stream>>>(h, Wf[l], Wsm[l], T);
    k_edge<<<5000, 256, 0, stream>>>(ei, ea, T, wpack + (size_t)l * 8192,
                                     bf[l], bs[l], accum);
    k_update<<<4000, 256, 0, stream>>>(h, accum);
  }
  k_pool<<<16000, 256, 0, stream>>>(h, batch, sums, cnt);
  k_final<<<1600, 128, 0, stream>>>(sums, cnt, Wlin, blin, out);
}

// Round 3
// 458.534 us; speedup vs baseline: 2.7545x; 1.7151x over previous
//
#include <hip/hip_runtime.h>
#include <math.h>

#define NN 32000
#define NE 320000
#define NG 1600

using frag_ab = __attribute__((ext_vector_type(8))) short;   // 8 bf16 (4 VGPRs)
using frag_cd = __attribute__((ext_vector_type(4))) float;   // 4 fp32

static __device__ __forceinline__ unsigned short f2bf(float f) {
  unsigned u = __builtin_bit_cast(unsigned, f);
  unsigned r = u + 0x7fff + ((u >> 16) & 1);   // RNE
  return (unsigned short)(r >> 16);
}
static __device__ __forceinline__ float bflo(unsigned u) {
  return __builtin_bit_cast(float, u << 16);
}
static __device__ __forceinline__ float bfhi(unsigned u) {
  return __builtin_bit_cast(float, u & 0xffff0000u);
}

// h = emb[x]; hb = bf16(h); accumb = 0
__global__ __launch_bounds__(256) void k_embed(const int* __restrict__ x,
                                               const float* __restrict__ emb,
                                               float* __restrict__ h,
                                               unsigned short* __restrict__ hb,
                                               unsigned short* __restrict__ accumb) {
  int idx = blockIdx.x * 256 + threadIdx.x;   // 512000 = 32000*16
  int n = idx >> 4;
  int c8 = (idx & 15) << 3;
  const float* e = emb + (size_t)x[n] * 128 + c8;
  float4 v0 = *(const float4*)e;
  float4 v1 = *(const float4*)(e + 4);
  float* hp = h + (size_t)n * 128 + c8;
  *(float4*)hp = v0;
  *(float4*)(hp + 4) = v1;
  ushort4 p0, p1;
  p0.x = f2bf(v0.x); p0.y = f2bf(v0.y); p0.z = f2bf(v0.z); p0.w = f2bf(v0.w);
  p1.x = f2bf(v1.x); p1.y = f2bf(v1.y); p1.z = f2bf(v1.z); p1.w = f2bf(v1.w);
  unsigned short* hbp = hb + (size_t)n * 128 + c8;
  *(ushort4*)hbp = p0;
  *(ushort4*)(hbp + 4) = p1;
  *(uint4*)(accumb + (size_t)n * 128 + c8) = make_uint4(0, 0, 0, 0);
}

// ea fp32 -> bf16
__global__ __launch_bounds__(256) void k_prep_ea(const float* __restrict__ ea,
                                                 unsigned short* __restrict__ eab) {
  int idx = blockIdx.x * 256 + threadIdx.x;   // 1,280,000 = NE*32/8
  const float* p = ea + (size_t)idx * 8;
  float4 v0 = *(const float4*)p;
  float4 v1 = *(const float4*)(p + 4);
  ushort4 o0, o1;
  o0.x = f2bf(v0.x); o0.y = f2bf(v0.y); o0.z = f2bf(v0.z); o0.w = f2bf(v0.w);
  o1.x = f2bf(v1.x); o1.y = f2bf(v1.y); o1.z = f2bf(v1.z); o1.w = f2bf(v1.w);
  unsigned short* q = eab + (size_t)idx * 8;
  *(ushort4*)q = o0;
  *(ushort4*)(q + 4) = o1;
}

// Pack ea-rows (256..287) of Wf/Ws, col-major [cc][k]:
// cc = w*64 + t*16 + c ; channel = w*32 + 2c + (t&1); t<2 -> Wf, else Ws
__global__ __launch_bounds__(256) void k_prep_we(const float* __restrict__ Wf1, const float* __restrict__ Ws1,
                                                 const float* __restrict__ Wf2, const float* __restrict__ Ws2,
                                                 const float* __restrict__ Wf3, const float* __restrict__ Ws3,
                                                 unsigned short* __restrict__ wedge) {
  int idx = blockIdx.x * 256 + threadIdx.x;    // 3*8192
  int l = idx >> 13;
  int r = idx & 8191;
  int cc = r >> 5;
  int k = r & 31;
  int w = cc >> 6, t = (cc >> 4) & 3, c = cc & 15;
  const float* Wf = (l == 0) ? Wf1 : (l == 1) ? Wf2 : Wf3;
  const float* Ws = (l == 0) ? Ws1 : (l == 1) ? Ws2 : Ws3;
  const float* W = (t < 2) ? Wf : Ws;
  int ch = w * 32 + 2 * c + (t & 1);
  wedge[(size_t)l * 8192 + cc * 32 + k] = f2bf(W[(size_t)(256 + k) * 128 + ch]);
}

// Pack node-GEMM weights B[k=128][n=512] col-major bf16 with even/odd tile permutation:
// cc in [0,512): seg = cc>>7 (dstF,srcF,dstS,srcS); within = cc&127;
// channel = (within&96) + 2*(within&15) + ((within>>4)&1); krow = (seg&1)*128 + k
__global__ __launch_bounds__(256) void k_prep_wg(const float* __restrict__ Wf1, const float* __restrict__ Ws1,
                                                 const float* __restrict__ Wf2, const float* __restrict__ Ws2,
                                                 const float* __restrict__ Wf3, const float* __restrict__ Ws3,
                                                 unsigned short* __restrict__ wgemm) {
  int idx = blockIdx.x * 256 + threadIdx.x;    // 3*65536
  int l = idx >> 16;
  int r = idx & 65535;
  int cc = r >> 7;
  int k = r & 127;
  int seg = cc >> 7, within = cc & 127;
  int ch = (within & 96) + ((within & 15) << 1) + ((within >> 4) & 1);
  const float* Wf = (l == 0) ? Wf1 : (l == 1) ? Wf2 : Wf3;
  const float* Ws = (l == 0) ? Ws1 : (l == 1) ? Ws2 : Ws3;
  const float* W = (seg < 2) ? Wf : Ws;
  int krow = (seg & 1) * 128 + k;
  wgemm[(size_t)l * 65536 + cc * 128 + k] = f2bf(W[(size_t)krow * 128 + ch]);
}

// T[node][512] bf16 = hb[32000,128] @ wgemm (MFMA). Block: 64 nodes x 128 cols.
__global__ __launch_bounds__(256) void k_gemm(const unsigned short* __restrict__ hb,
                                              const unsigned short* __restrict__ wgemmL,
                                              unsigned short* __restrict__ T) {
  __shared__ short sA[64 * 136];
  __shared__ short sB[128 * 136];
  int m0 = blockIdx.x * 64;
  int n0 = blockIdx.y * 128;
  int tid = threadIdx.x;
#pragma unroll
  for (int i = 0; i < 4; ++i) {          // A: 1024 uint4
    int idx = tid + i * 256;
    int row = idx >> 4, chk = idx & 15;
    uint4 v = *(const uint4*)(hb + (size_t)(m0 + row) * 128 + chk * 8);
    *(uint4*)&sA[row * 136 + chk * 8] = v;
  }
#pragma unroll
  for (int i = 0; i < 8; ++i) {          // B: 2048 uint4
    int idx = tid + i * 256;
    int col = idx >> 4, chk = idx & 15;
    uint4 v = *(const uint4*)(wgemmL + (size_t)(n0 + col) * 128 + chk * 8);
    *(uint4*)&sB[col * 136 + chk * 8] = v;
  }
  __syncthreads();
  int w = tid >> 6, lane = tid & 63, c = lane & 15, q = lane >> 4;
  frag_cd acc[4][2];
#pragma unroll
  for (int mt = 0; mt < 4; ++mt)
#pragma unroll
    for (int t = 0; t < 2; ++t) acc[mt][t] = (frag_cd){0.f, 0.f, 0.f, 0.f};
#pragma unroll
  for (int ks = 0; ks < 4; ++ks) {
    frag_ab Af[4], Bf[2];
#pragma unroll
    for (int mt = 0; mt < 4; ++mt)
      Af[mt] = *(const frag_ab*)&sA[(mt * 16 + c) * 136 + ks * 32 + q * 8];
#pragma unroll
    for (int t = 0; t < 2; ++t)
      Bf[t] = *(const frag_ab*)&sB[(w * 32 + t * 16 + c) * 136 + ks * 32 + q * 8];
#pragma unroll
    for (int mt = 0; mt < 4; ++mt)
#pragma unroll
      for (int t = 0; t < 2; ++t)
        acc[mt][t] = __builtin_amdgcn_mfma_f32_16x16x32_bf16(Af[mt], Bf[t], acc[mt][t], 0, 0, 0);
  }
  // store packed pairs: channel n0 + w*32 + 2c (+1)
  int nbase = n0 + w * 32 + 2 * c;
#pragma unroll
  for (int mt = 0; mt < 4; ++mt) {
#pragma unroll
    for (int r = 0; r < 4; ++r) {
      int node = m0 + mt * 16 + q * 4 + r;
      unsigned pk = (unsigned)f2bf(acc[mt][0][r]) | ((unsigned)f2bf(acc[mt][1][r]) << 16);
      *(unsigned*)(T + (size_t)node * 512 + nbase) = pk;
    }
  }
}

// Per-edge MFMA + gather + packed bf16 atomics.
__global__ __launch_bounds__(256) void k_edge(const int* __restrict__ ei,
                                              const unsigned short* __restrict__ eab,
                                              const unsigned short* __restrict__ T,
                                              const unsigned short* __restrict__ wedgeL,
                                              const float* __restrict__ bf,
                                              const float* __restrict__ bs,
                                              unsigned short* __restrict__ accumb) {
  __shared__ short sA[64 * 40];    // ea tile bf16
  __shared__ short sB[256 * 40];   // packed W bf16
  __shared__ float sbf[128], sbs[128];
  __shared__ int sSrc[64], sDst[64];
  int tid = threadIdx.x;
  int e0 = blockIdx.x * 64;
  {  // ea tile: 2048 shorts = 256 uint4
    int row = tid >> 2, qq = tid & 3;
    uint4 v = *(const uint4*)(eab + (size_t)e0 * 32 + tid * 8);
    *(uint4*)&sA[row * 40 + qq * 8] = v;
  }
#pragma unroll
  for (int i = 0; i < 4; ++i) {   // weights: 1024 uint4
    int idx = tid + i * 256;
    int col = idx >> 2, qq = idx & 3;
    uint4 v = *(const uint4*)(wedgeL + (size_t)col * 32 + qq * 8);
    *(uint4*)&sB[col * 40 + qq * 8] = v;
  }
  if (tid < 128) {
    sbf[tid] = bf[tid];
    sbs[tid] = bs[tid];
  } else if (tid < 192) {
    sSrc[tid - 128] = ei[e0 + tid - 128];
  } else {
    sDst[tid - 192] = ei[NE + e0 + tid - 192];
  }
  __syncthreads();

  int w = tid >> 6;
  int lane = tid & 63;
  int c = lane & 15;
  int q = lane >> 4;

  frag_ab Af[4], Bf[4];
#pragma unroll
  for (int et = 0; et < 4; ++et)
    Af[et] = *(const frag_ab*)&sA[(et * 16 + c) * 40 + q * 8];
#pragma unroll
  for (int t = 0; t < 4; ++t)
    Bf[t] = *(const frag_ab*)&sB[(w * 64 + t * 16 + c) * 40 + q * 8];

  frag_cd acc[4][4];
#pragma unroll
  for (int et = 0; et < 4; ++et)
#pragma unroll
    for (int t = 0; t < 4; ++t)
      acc[et][t] = (frag_cd){0.f, 0.f, 0.f, 0.f};
#pragma unroll
  for (int et = 0; et < 4; ++et)
#pragma unroll
    for (int t = 0; t < 4; ++t)
      acc[et][t] = __builtin_amdgcn_mfma_f32_16x16x32_bf16(Af[et], Bf[t], acc[et][t], 0, 0, 0);

  int ch = w * 32 + 2 * c;   // even; lane owns (ch, ch+1)
  float bf0 = sbf[ch], bf1 = sbf[ch + 1];
  float bs0 = sbs[ch], bs1 = sbs[ch + 1];

#pragma unroll
  for (int et = 0; et < 4; ++et) {
#pragma unroll
    for (int r = 0; r < 4; ++r) {
      int e = et * 16 + q * 4 + r;
      int s = sSrc[e], d = sDst[e];
      const unsigned short* Td = T + (size_t)d * 512;
      const unsigned short* Ts = T + (size_t)s * 512;
      unsigned fd = *(const unsigned*)(Td + ch);
      unsigned fs = *(const unsigned*)(Ts + 128 + ch);
      unsigned sd = *(const unsigned*)(Td + 256 + ch);
      unsigned ss = *(const unsigned*)(Ts + 384 + ch);
      float xf0 = acc[et][0][r] + bflo(fd) + bflo(fs) + bf0;
      float xf1 = acc[et][1][r] + bfhi(fd) + bfhi(fs) + bf1;
      float xs0 = acc[et][2][r] + bflo(sd) + bflo(ss) + bs0;
      float xs1 = acc[et][3][r] + bfhi(sd) + bfhi(ss) + bs1;
      float g0 = __builtin_amdgcn_rcpf(1.f + __expf(-xf0));
      float g1 = __builtin_amdgcn_rcpf(1.f + __expf(-xf1));
      float sp0 = fmaxf(xs0, 0.f) + __logf(1.f + __expf(-fabsf(xs0)));
      float sp1 = fmaxf(xs1, 0.f) + __logf(1.f + __expf(-fabsf(xs1)));
      float m0 = g0 * sp0, m1 = g1 * sp1;
      unsigned pk = (unsigned)f2bf(m0) | ((unsigned)f2bf(m1) << 16);
      unsigned short* p = accumb + (size_t)d * 128 + ch;
      asm volatile("global_atomic_pk_add_bf16 %0, %1, off" :: "v"(p), "v"(pk) : "memory");
    }
  }
}

// h = relu(h + accumb); hb = bf16(h); accumb = 0
__global__ __launch_bounds__(256) void k_update(float* __restrict__ h,
                                                unsigned short* __restrict__ hb,
                                                unsigned short* __restrict__ accumb) {
  int idx = blockIdx.x * 256 + threadIdx.x;   // 512000
  size_t off = (size_t)idx * 8;
  uint4 a = *(uint4*)(accumb + off);
  float4 v0 = *(float4*)(h + off);
  float4 v1 = *(float4*)(h + off + 4);
  v0.x = fmaxf(v0.x + bflo(a.x), 0.f);
  v0.y = fmaxf(v0.y + bfhi(a.x), 0.f);
  v0.z = fmaxf(v0.z + bflo(a.y), 0.f);
  v0.w = fmaxf(v0.w + bfhi(a.y), 0.f);
  v1.x = fmaxf(v1.x + bflo(a.z), 0.f);
  v1.y = fmaxf(v1.y + bfhi(a.z), 0.f);
  v1.z = fmaxf(v1.z + bflo(a.w), 0.f);
  v1.w = fmaxf(v1.w + bfhi(a.w), 0.f);
  *(float4*)(h + off) = v0;
  *(float4*)(h + off + 4) = v1;
  ushort4 p0, p1;
  p0.x = f2bf(v0.x); p0.y = f2bf(v0.y); p0.z = f2bf(v0.z); p0.w = f2bf(v0.w);
  p1.x = f2bf(v1.x); p1.y = f2bf(v1.y); p1.z = f2bf(v1.z); p1.w = f2bf(v1.w);
  *(ushort4*)(hb + off) = p0;
  *(ushort4*)(hb + off + 4) = p1;
  *(uint4*)(accumb + off) = make_uint4(0, 0, 0, 0);
}

__global__ __launch_bounds__(256) void k_pool(const float* __restrict__ h,
                                              const int* __restrict__ batch,
                                              float* __restrict__ sums,
                                              float* __restrict__ cnt) {
  int n = blockIdx.x * 2 + (threadIdx.x >> 7);
  int c = threadIdx.x & 127;
  int g = batch[n];
  atomicAdd(sums + (size_t)g * 128 + c, h[(size_t)n * 128 + c]);
  if (c == 0) atomicAdd(cnt + g, 1.f);
}

__global__ __launch_bounds__(128) void k_final(const float* __restrict__ sums,
                                               const float* __restrict__ cnt,
                                               const float* __restrict__ Wlin,
                                               const float* __restrict__ blin,
                                               float* __restrict__ out) {
  __shared__ float p[128];
  int g = blockIdx.x, c = threadIdx.x;
  float inv = 1.f / fmaxf(cnt[g], 1.f);
  p[c] = sums[(size_t)g * 128 + c] * inv;
  __syncthreads();
  float acc = blin[c];
#pragma unroll 8
  for (int k = 0; k < 128; ++k) acc += p[k] * Wlin[k * 128 + c];
  out[(size_t)g * 128 + c] = acc;
}

extern "C" void kernel_launch(void* const* d_in, const int* in_sizes, int n_in,
                              void* d_out, int out_size, void* d_ws, size_t ws_size,
                              hipStream_t stream) {
  const int* x = (const int*)d_in[0];
  const int* ei = (const int*)d_in[1];
  const float* ea = (const float*)d_in[2];
  const int* batch = (const int*)d_in[3];
  const float* emb = (const float*)d_in[4];
  const float* Wf[3] = {(const float*)d_in[5], (const float*)d_in[9], (const float*)d_in[13]};
  const float* bf[3] = {(const float*)d_in[6], (const float*)d_in[10], (const float*)d_in[14]};
  const float* Wsm[3] = {(const float*)d_in[7], (const float*)d_in[11], (const float*)d_in[15]};
  const float* bs[3] = {(const float*)d_in[8], (const float*)d_in[12], (const float*)d_in[16]};
  const float* Wlin = (const float*)d_in[17];
  const float* blin = (const float*)d_in[18];
  float* out = (float*)d_out;

  char* ws = (char*)d_ws;
  float* h = (float*)ws;                                          ws += (size_t)NN * 128 * 4;
  unsigned short* hb = (unsigned short*)ws;                       ws += (size_t)NN * 128 * 2;
  unsigned short* accumb = (unsigned short*)ws;                   ws += (size_t)NN * 128 * 2;
  unsigned short* T = (unsigned short*)ws;                        ws += (size_t)NN * 512 * 2;
  unsigned short* eab = (unsigned short*)ws;                      ws += (size_t)NE * 32 * 2;
  unsigned short* wedge = (unsigned short*)ws;                    ws += 3 * 8192 * 2;
  unsigned short* wgemm = (unsigned short*)ws;                    ws += 3 * 65536 * 2;
  float* sums = (float*)ws;                                       ws += (size_t)NG * 128 * 4;
  float* cnt = (float*)ws;

  hipMemsetAsync(sums, 0, ((size_t)NG * 128 + NG) * sizeof(float), stream);
  k_prep_ea<<<5000, 256, 0, stream>>>(ea, eab);
  k_prep_we<<<96, 256, 0, stream>>>(Wf[0], Wsm[0], Wf[1], Wsm[1], Wf[2], Wsm[2], wedge);
  k_prep_wg<<<768, 256, 0, stream>>>(Wf[0], Wsm[0], Wf[1], Wsm[1], Wf[2], Wsm[2], wgemm);
  k_embed<<<2000, 256, 0, stream>>>(x, emb, h, hb, accumb);
  for (int l = 0; l < 3; ++l) {
    k_gemm<<<dim3(500, 4), 256, 0, stream>>>(hb, wgemm + (size_t)l * 65536, T);
    k_edge<<<5000, 256, 0, stream>>>(ei, eab, T, wedge + (size_t)l * 8192,
                                     bf[l], bs[l], accumb);
    k_update<<<2000, 256, 0, stream>>>(h, hb, accumb);
  }
  k_pool<<<16000, 256, 0, stream>>>(h, batch, sums, cnt);
  k_final<<<1600, 128, 0, stream>>>(sums, cnt, Wlin, blin, out);
}